// Round 13
// baseline (183.984 us; speedup 1.0000x reference)
//
#include <hip/hip_runtime.h>

// Deformable conv v1 fwd: B=4, C=64, H=W=128, K=3, O=64, fp32 in/out.
// bf16 split MFMA: A-side (weights) hi+lo planes, B-side (data) single RNE
// bf16. TWO-KERNEL GRAPH:
//   K1 prep_and_transpose: weight planes + NCHW->NHWC (independent work).
//   K2 dcn_fused: Phase A offset GEMM (register-only, dedicated offs LDS)
//      -> Phase B bilinear coef -> Phase C verified R10 tap loop
//      (2 barriers/tap, single buffer, XCD swizzle, gather hoist).
//
// ws layout (bytes):
//   [0)        whi   u16[9][64][64]   (w: [tap][o][c] hi plane)
//   [73728)    wlo   u16[9][64][64]
//   [147456)   wofh  u16[9][32][64]   (w_off padded 18->32 rows, [tap][ch][c])
//   [184320)   wofl  u16[9][32][64]
//   [221184)   xt    f32[4][128][128][64]  (NHWC)
//   end 16998400 (~16.2 MB)

typedef unsigned short u16;
typedef __attribute__((ext_vector_type(8))) short bf16x8;
typedef __attribute__((ext_vector_type(4))) float f32x4;
#define MFMA __builtin_amdgcn_mfma_f32_16x16x32_bf16

__device__ __forceinline__ void bsplit(float v, u16& h, u16& l) {
  unsigned u = __float_as_uint(v);
  unsigned hb = (u + 0x7fffu + ((u >> 16) & 1u)) & 0xffff0000u;
  h = (u16)(hb >> 16);
  float r = v - __uint_as_float(hb);
  unsigned u2 = __float_as_uint(r);
  l = (u16)((u2 + 0x7fffu + ((u2 >> 16) & 1u)) >> 16);
}

__device__ __forceinline__ u16 brnd(float v) {   // fp32 -> bf16 RNE
  unsigned u = __float_as_uint(v);
  return (u16)((u + 0x7fffu + ((u >> 16) & 1u)) >> 16);
}

// K1: blocks [0,1024): NCHW->NHWC transpose; blocks [1024,1088): weight prep.
__global__ __launch_bounds__(256) void prep_and_transpose(
    const float* __restrict__ x, const float* __restrict__ w,
    const float* __restrict__ w_off, float* __restrict__ xt,
    u16* __restrict__ whi, u16* __restrict__ wlo,
    u16* __restrict__ wofh, u16* __restrict__ wofl) {
  __shared__ float tile[64][65];
  int blk = blockIdx.x;
  if (blk < 1024) {
    int wchunk = blk & 1;
    int h = (blk >> 1) & 127;
    int b = blk >> 8;
    int w0 = wchunk * 64;
    int r = threadIdx.x >> 6;
    int lane = threadIdx.x & 63;
#pragma unroll
    for (int i = 0; i < 16; i++) {
      int c = r + i * 4;
      tile[c][lane] = x[(((size_t)(b * 64 + c) * 128) + h) * 128 + w0 + lane];
    }
    __syncthreads();
#pragma unroll
    for (int i = 0; i < 16; i++) {
      int wi = r + i * 4;
      xt[(((size_t)(b * 128 + h) * 128) + w0 + wi) * 64 + lane] = tile[lane][wi];
    }
  } else {
    int t = (blk - 1024) * 256 + threadIdx.x;
    const int stride = 64 * 256;
    for (int i = t; i < 9 * 64 * 64; i += stride) {
      int tap = i >> 12, o = (i >> 6) & 63, c = i & 63;
      u16 h, l;
      bsplit(w[o * 576 + c * 9 + tap], h, l);
      whi[i] = h; wlo[i] = l;
    }
    for (int i = t; i < 9 * 32 * 64; i += stride) {
      int tap = i >> 11, ch = (i >> 6) & 31, c = i & 63;
      float v = (ch < 18) ? w_off[ch * 576 + c * 9 + tap] : 0.f;
      u16 h, l;
      bsplit(v, h, l);
      wofh[i] = h; wofl[i] = l;
    }
  }
}

// K2: fused offset GEMM + bilinear coef + sample/GEMM tap loop.
#define SWZ(p, byt) ((byt) ^ (((p) & 7) << 4))
__global__ __launch_bounds__(256) void dcn_fused(
    const float* __restrict__ xt,
    const u16* __restrict__ whi, const u16* __restrict__ wlo,
    const u16* __restrict__ wofh, const u16* __restrict__ wofl,
    const float* __restrict__ b_off, const float* __restrict__ bias,
    float* __restrict__ out) {
  __shared__ __align__(16) float cw_lds[576][4];   // bilinear weights
  __shared__ __align__(16) int   ci_lds[576][4];   // corner float-index offsets
  __shared__ __align__(16) u16   shi[64 * 64];     // [p][c] bf16, XOR-swizzled
  __shared__ __align__(16) float offs[64][20];     // offset conv result (18 used)

  int blk = blockIdx.x;
  int wg = ((blk & 7) << 7) | (blk >> 3);          // bijective XCD chunk swizzle
  int wc = wg & 1, h = (wg >> 1) & 127, b = wg >> 8;
  int w0 = wc * 64;
  int tid = threadIdx.x, lane = tid & 63, wave = tid >> 6;
  int lm = lane & 15, lg = lane >> 4;
  const float* xbase = xt + (size_t)b * (128 * 128 * 64);

  // ---------- Phase A: offset conv GEMM for this block's 64 px ----------
  // A = wof[tap][ch(32)][c] hi/lo planes; B = x px-rows as RNE bf16.
  // D[ch][px]: lane holds ch = 4*lg + r (oa0) / 16+4*lg+r (oa1), px = wave*16+lm.
  {
    f32x4 oa0 = (f32x4)0.f, oa1 = (f32x4)0.f;
#pragma unroll 1
    for (int tap = 0; tap < 9; tap++) {
      int ky = tap / 3, kx = tap - ky * 3;
      int y = h + ky - 1;
      if ((unsigned)y >= 128u) continue;           // block-uniform
#pragma unroll
      for (int kc = 0; kc < 2; kc++) {
        const u16* ah = wofh + tap * 2048 + lm * 64 + kc * 32 + lg * 8;
        const u16* al = wofl + tap * 2048 + lm * 64 + kc * 32 + lg * 8;
        bf16x8 a0h = *(const bf16x8*)ah;
        bf16x8 a0l = *(const bf16x8*)al;
        bf16x8 a1h = *(const bf16x8*)(ah + 1024);
        bf16x8 a1l = *(const bf16x8*)(al + 1024);
        int xx = w0 + wave * 16 + lm + kx - 1;
        bool valid = (unsigned)xx < 128u;
        int xcl = min(max(xx, 0), 127);
        const float* xp = xbase + ((size_t)(y * 128 + xcl)) * 64 + kc * 32 + lg * 8;
        float4 xa = *(const float4*)xp;
        float4 xd = *(const float4*)(xp + 4);
        if (!valid) { xa = make_float4(0, 0, 0, 0); xd = make_float4(0, 0, 0, 0); }
        bf16x8 bh;
        bh[0] = brnd(xa.x); bh[1] = brnd(xa.y);
        bh[2] = brnd(xa.z); bh[3] = brnd(xa.w);
        bh[4] = brnd(xd.x); bh[5] = brnd(xd.y);
        bh[6] = brnd(xd.z); bh[7] = brnd(xd.w);
        oa0 = MFMA(a0h, bh, oa0, 0, 0, 0);
        oa0 = MFMA(a0l, bh, oa0, 0, 0, 0);
        oa1 = MFMA(a1h, bh, oa1, 0, 0, 0);
        oa1 = MFMA(a1l, bh, oa1, 0, 0, 0);
      }
    }
    int px = wave * 16 + lm;
    float4 bo = *(const float4*)(b_off + 4 * lg);
    offs[px][4 * lg + 0] = oa0[0] + bo.x;
    offs[px][4 * lg + 1] = oa0[1] + bo.y;
    offs[px][4 * lg + 2] = oa0[2] + bo.z;
    offs[px][4 * lg + 3] = oa0[3] + bo.w;
    if (lg == 0) {
      offs[px][16] = oa1[0] + b_off[16];
      offs[px][17] = oa1[1] + b_off[17];
    }
  }
  __syncthreads();   // offs visible

  // ---------- Phase B: bilinear coef + corner offsets ----------
#pragma unroll 1
  for (int it = tid; it < 576; it += 256) {
    int p = it / 9, k = it - p * 9;
    int ky = k / 3, kx = k - ky * 3;
    float oy = offs[p][2 * k];
    float ox = offs[p][2 * k + 1];
    float yf = (float)(h + ky - 1) + oy;
    float xf = (float)(w0 + p + kx - 1) + ox;
    float y0f = floorf(yf), x0f = floorf(xf);
    float wy = yf - y0f, wx = xf - x0f;
    int y0 = (int)y0f, x0 = (int)x0f;
    int y1 = y0 + 1, x1 = x0 + 1;
    float w00 = (1.f - wy) * (1.f - wx);
    float w01 = (1.f - wy) * wx;
    float w10 = wy * (1.f - wx);
    float w11 = wy * wx;
    bool vy0 = (unsigned)y0 < 128u, vy1 = (unsigned)y1 < 128u;
    bool vx0 = (unsigned)x0 < 128u, vx1 = (unsigned)x1 < 128u;
    if (!(vy0 && vx0)) w00 = 0.f;
    if (!(vy0 && vx1)) w01 = 0.f;
    if (!(vy1 && vx0)) w10 = 0.f;
    if (!(vy1 && vx1)) w11 = 0.f;
    int y0c = min(max(y0, 0), 127), y1c = min(max(y1, 0), 127);
    int x0c = min(max(x0, 0), 127), x1c = min(max(x1, 0), 127);
    *(float4*)cw_lds[it] = make_float4(w00, w01, w10, w11);
    *(int4*)ci_lds[it] =
        make_int4((y0c * 128 + x0c) * 64, (y0c * 128 + x1c) * 64,
                  (y1c * 128 + x0c) * 64, (y1c * 128 + x1c) * 64);
  }
  __syncthreads();

  // ---------- Phase C: verified R10 tap loop ----------
  f32x4 acc[4];
#pragma unroll
  for (int i = 0; i < 4; i++) acc[i] = (f32x4)0.f;

  float g[16][4];

  // prefetch tap 0 gathers
#pragma unroll
  for (int i = 0; i < 16; i++) {
    int4 ci = *(const int4*)ci_lds[(wave * 16 + i) * 9 + 0];
    g[i][0] = xbase[ci.x + lane];
    g[i][1] = xbase[ci.y + lane];
    g[i][2] = xbase[ci.z + lane];
    g[i][3] = xbase[ci.w + lane];
  }

#pragma unroll 1
  for (int tap = 0; tap < 9; tap++) {
    // combine tap's gathers -> LDS (single buffer)
#pragma unroll
    for (int i = 0; i < 16; i++) {
      int p = wave * 16 + i;
      float4 cwv = *(const float4*)cw_lds[p * 9 + tap];
      float v = cwv.x * g[i][0] + cwv.y * g[i][1] +
                cwv.z * g[i][2] + cwv.w * g[i][3];
      int byt = SWZ(p, p * 128 + lane * 2);
      *(u16*)((char*)shi + byt) = brnd(v);
    }
    __syncthreads();                 // B1: tile visible

    // hoisted gathers for tap+1 (registers only, overlap with MFMA)
    if (tap < 8) {
#pragma unroll
      for (int i = 0; i < 16; i++) {
        int4 ci = *(const int4*)ci_lds[(wave * 16 + i) * 9 + tap + 1];
        g[i][0] = xbase[ci.x + lane];
        g[i][1] = xbase[ci.y + lane];
        g[i][2] = xbase[ci.z + lane];
        g[i][3] = xbase[ci.w + lane];
      }
    }

    // MFMA for this tap: A hi/lo x B hi
    const u16* wh = whi + tap * 4096 + (wave * 16 + lm) * 64 + lg * 8;
    const u16* wl = wlo + tap * 4096 + (wave * 16 + lm) * 64 + lg * 8;
    bf16x8 ah0 = *(const bf16x8*)wh;
    bf16x8 ah1 = *(const bf16x8*)(wh + 32);
    bf16x8 al0 = *(const bf16x8*)wl;
    bf16x8 al1 = *(const bf16x8*)(wl + 32);
#pragma unroll
    for (int pt = 0; pt < 4; pt++) {
      int p = pt * 16 + lm;
      int byt0 = SWZ(p, p * 128 + lg * 16);
      int byt1 = SWZ(p, p * 128 + 64 + lg * 16);
      bf16x8 bh0 = *(const bf16x8*)((char*)shi + byt0);
      bf16x8 bh1 = *(const bf16x8*)((char*)shi + byt1);
      acc[pt] = MFMA(ah0, bh0, acc[pt], 0, 0, 0);
      acc[pt] = MFMA(al0, bh0, acc[pt], 0, 0, 0);
      acc[pt] = MFMA(ah1, bh1, acc[pt], 0, 0, 0);
      acc[pt] = MFMA(al1, bh1, acc[pt], 0, 0, 0);
    }
    __syncthreads();                 // B2: reads done before next combine
  }

  // ---------- store: lane holds D[o = wave*16+4*lg+r][p = pt*16+lm] ----------
  float4 bv = *(const float4*)(bias + wave * 16 + 4 * lg);
  size_t ob = ((size_t)(b * 64 + wave * 16 + 4 * lg)) * 16384 + h * 128 + w0;
#pragma unroll
  for (int pt = 0; pt < 4; pt++) {
#pragma unroll
    for (int r = 0; r < 4; r++) {
      float bb = (r == 0) ? bv.x : (r == 1) ? bv.y : (r == 2) ? bv.z : bv.w;
      out[ob + (size_t)r * 16384 + pt * 16 + lm] = acc[pt][r] + bb;
    }
  }
}

extern "C" void kernel_launch(void* const* d_in, const int* in_sizes, int n_in,
                              void* d_out, int out_size, void* d_ws, size_t ws_size,
                              hipStream_t stream) {
  const float* x     = (const float*)d_in[0];
  const float* w_off = (const float*)d_in[1];
  const float* b_off = (const float*)d_in[2];
  const float* w     = (const float*)d_in[3];
  const float* b     = (const float*)d_in[4];
  float* out = (float*)d_out;
  char* ws = (char*)d_ws;

  u16*   whi  = (u16*)(ws);
  u16*   wlo  = (u16*)(ws + 73728);
  u16*   wofh = (u16*)(ws + 147456);
  u16*   wofl = (u16*)(ws + 184320);
  float* xtw  = (float*)(ws + 221184);

  prep_and_transpose<<<1088, 256, 0, stream>>>(x, w, w_off, xtw, whi, wlo, wofh, wofl);
  dcn_fused<<<1024, 256, 0, stream>>>(xtw, whi, wlo, wofh, wofl, b_off, b, out);
}